// Round 5
// baseline (557.215 us; speedup 1.0000x reference)
//
#include <hip/hip_runtime.h>

#define B_DIM   512
#define IN_DIM  65536
#define OUT_DIM 16384
#define K_DIM   32

static __device__ __forceinline__ unsigned short f2bf(float f) {
    unsigned u = __builtin_bit_cast(unsigned, f);
    unsigned r = (u + 0x7FFFu + ((u >> 16) & 1u)) >> 16;   // round-to-nearest-even
    return (unsigned short)r;
}

static __device__ __forceinline__ float fcomp(float4 v, int c) {
    switch (c & 3) { case 0: return v.x; case 1: return v.y; case 2: return v.z; default: return v.w; }
}

// ---------------------------------------------------------------------------
// Kernel 1: transpose + fp32->bf16, NO LDS.
// Block = 512 threads, tile = 32 in-cols x all 512 b. Each thread owns one
// b-row and reads a FULL 128-B line; every line of x read exactly once
// chip-wide. Writes: consecutive lanes = consecutive b -> full 1-KiB xT rows
// per block.
// ---------------------------------------------------------------------------
__global__ __launch_bounds__(512) void transpose_bf16_k(const float* __restrict__ x,
                                                        unsigned short* __restrict__ xT) {
    const int c0 = blockIdx.x * 32;
    const int b  = threadIdx.x;
    const float4* p = (const float4*)(x + (size_t)b * IN_DIM + c0);
    float4 v[8];
    #pragma unroll
    for (int j = 0; j < 8; ++j) v[j] = p[j];
    #pragma unroll
    for (int c = 0; c < 32; ++c) {
        xT[(size_t)(c0 + c) * B_DIM + b] = f2bf(fcomp(v[c >> 2], c));
    }
}

// ---------------------------------------------------------------------------
// Kernel 2: main. Block = 1024 threads (16 waves), owns 32 outputs x 512 b.
// Inner structure identical to the verified round-2 loop: each WAVE owns 2
// outputs, each LANE owns 8 b's, one row-gather = ONE global_load_dwordx4
// per wave (1 KiB payload). 512 blocks x 16 waves = 8192 waves, LDS 64 KiB
// -> 2 blocks/CU, 32 waves/CU.
//
// KEY CHANGE (round-3 post-mortem): a block now owns 32 CONSECUTIVE outputs
// = exactly one 128-B out line per b, written WHOLE by 8 lanes of one wave
// in a single wave-instruction. Rounds 0/2/3 shared each line across 4
// blocks on 4 XCDs with 16-B partial stores; at 80% occupancy L2 thrash
// turned every partial store into an RMW line round-trip (FETCH +268 MB,
// WRITE 573 MB = 17x output). Full-line single-owner stores remove the RMW
// structurally, independent of cache timing.
//
// LDS corner-turn buffer is [32][512] (power-of-2) with an XOR column
// swizzle col = b ^ (((o>>2)&7)<<2): epilogue lanes that share b read 8
// distinct rows -> 8 distinct banks (<=2-way overall) instead of 8-way.
// ---------------------------------------------------------------------------
__global__ __launch_bounds__(1024, 8) void sparse_main(const unsigned short* __restrict__ xT,
                                                       const int*   __restrict__ idxp,
                                                       const float* __restrict__ wp,
                                                       const float* __restrict__ biasp,
                                                       float*       __restrict__ out) {
    __shared__ float lds[32][512];   // 64 KiB
    const int o_blk = blockIdx.x * 32;
    const int t    = threadIdx.x;
    const int wid  = t >> 6;         // 0..15
    const int lane = t & 63;
    const int b8   = lane * 8;       // this thread's 8 b's

    // wave's idx/w tile: 2 o's x 32 k = 64 scalars = one per lane
    const int   iv = idxp[o_blk * K_DIM + wid * 64 + lane];
    const float wv = wp  [o_blk * K_DIM + wid * 64 + lane];

    float4 a0[2], a1[2];
    #pragma unroll
    for (int oo = 0; oo < 2; ++oo) {
        a0[oo] = make_float4(0.f, 0.f, 0.f, 0.f);
        a1[oo] = make_float4(0.f, 0.f, 0.f, 0.f);
    }

    #pragma unroll
    for (int oo = 0; oo < 2; ++oo) {
        #pragma unroll
        for (int k = 0; k < K_DIM; ++k) {
            const int L = oo * 32 + k;          // lane holding (oo,k)'s idx/w
            const int   sidx = __builtin_amdgcn_readlane(iv, L);
            const float sw   = __int_as_float(
                __builtin_amdgcn_readlane(__float_as_int(wv), L));
            const uint4 u = *(const uint4*)(xT + ((size_t)sidx << 9) + b8);
            a0[oo].x = fmaf(sw, __int_as_float(u.x << 16),          a0[oo].x);
            a0[oo].y = fmaf(sw, __int_as_float(u.x & 0xFFFF0000u),  a0[oo].y);
            a0[oo].z = fmaf(sw, __int_as_float(u.y << 16),          a0[oo].z);
            a0[oo].w = fmaf(sw, __int_as_float(u.y & 0xFFFF0000u),  a0[oo].w);
            a1[oo].x = fmaf(sw, __int_as_float(u.z << 16),          a1[oo].x);
            a1[oo].y = fmaf(sw, __int_as_float(u.z & 0xFFFF0000u),  a1[oo].y);
            a1[oo].z = fmaf(sw, __int_as_float(u.w << 16),          a1[oo].z);
            a1[oo].w = fmaf(sw, __int_as_float(u.w & 0xFFFF0000u),  a1[oo].w);
        }
    }

    #pragma unroll
    for (int oo = 0; oo < 2; ++oo) {
        const int ow = wid * 2 + oo;
        const int sc = ((ow >> 2) & 7) << 2;     // column XOR swizzle for row ow
        const float bv = biasp[o_blk + ow];
        a0[oo].x += bv; a0[oo].y += bv; a0[oo].z += bv; a0[oo].w += bv;
        a1[oo].x += bv; a1[oo].y += bv; a1[oo].z += bv; a1[oo].w += bv;
        *(float4*)(&lds[ow][b8 ^ sc])       = a0[oo];
        *(float4*)(&lds[ow][(b8 + 4) ^ sc]) = a1[oo];
    }
    __syncthreads();

    // corner-turn write: 512 b x 32 o = 16384 floats, 4 passes of 4096.
    // 8 consecutive lanes cover one b's full 32-o segment = one whole 128-B
    // line per b, single-owner, single wave-instruction.
    #pragma unroll
    for (int p = 0; p < 4; ++p) {
        const int q = p * 4096 + t * 4;
        const int b = q >> 5;            // p*128 + t/8
        const int o = q & 31;            // (t&7)*4
        const int sc = ((o >> 2) & 7) << 2;
        const int col = b ^ sc;
        float4 v;
        v.x = lds[o + 0][col];
        v.y = lds[o + 1][col];
        v.z = lds[o + 2][col];
        v.w = lds[o + 3][col];
        *(float4*)(out + (size_t)b * OUT_DIM + o_blk + o) = v;
    }
}

// ---------------------------------------------------------------------------
// Fallback (workspace too small): direct gather, correct but slow.
// ---------------------------------------------------------------------------
__global__ void sparse_fallback(const float* __restrict__ x,
                                const int*   __restrict__ idxp,
                                const float* __restrict__ wp,
                                const float* __restrict__ biasp,
                                float*       __restrict__ out) {
    const int i = blockIdx.x * blockDim.x + threadIdx.x;
    if (i >= B_DIM * OUT_DIM) return;
    const int b = i / OUT_DIM;
    const int o = i % OUT_DIM;
    float a = biasp[o];
    for (int k = 0; k < K_DIM; ++k) {
        const int idx = idxp[o * K_DIM + k];
        a = fmaf(wp[o * K_DIM + k], x[(size_t)b * IN_DIM + idx], a);
    }
    out[i] = a;
}

extern "C" void kernel_launch(void* const* d_in, const int* in_sizes, int n_in,
                              void* d_out, int out_size, void* d_ws, size_t ws_size,
                              hipStream_t stream) {
    const float* x       = (const float*)d_in[0];
    const int*   indices = (const int*)  d_in[1];
    const float* weight  = (const float*)d_in[2];
    const float* bias    = (const float*)d_in[3];
    float*       out     = (float*)d_out;

    const size_t need = (size_t)IN_DIM * B_DIM * sizeof(unsigned short);  // 64 MiB
    if (ws_size >= need) {
        unsigned short* xT = (unsigned short*)d_ws;
        transpose_bf16_k<<<IN_DIM / 32, 512, 0, stream>>>(x, xT);
        sparse_main<<<OUT_DIM / 32, 1024, 0, stream>>>(xT, indices, weight, bias, out);
    } else {
        const int n = B_DIM * OUT_DIM;
        sparse_fallback<<<(n + 255) / 256, 256, 0, stream>>>(x, indices, weight, bias, out);
    }
}

// Round 6
// 351.487 us; speedup vs baseline: 1.5853x; 1.5853x over previous
//
#include <hip/hip_runtime.h>

#define B_DIM   512
#define IN_DIM  65536
#define OUT_DIM 16384
#define K_DIM   32

static __device__ __forceinline__ unsigned short f2bf(float f) {
    unsigned u = __builtin_bit_cast(unsigned, f);
    unsigned r = (u + 0x7FFFu + ((u >> 16) & 1u)) >> 16;   // round-to-nearest-even
    return (unsigned short)r;
}

static __device__ __forceinline__ float fcomp(float4 v, int c) {
    switch (c & 3) { case 0: return v.x; case 1: return v.y; case 2: return v.z; default: return v.w; }
}

// ---------------------------------------------------------------------------
// Kernel 1: transpose + fp32->bf16, NO LDS.
// Block = 512 threads, tile = 32 in-cols x all 512 b. Each thread owns one
// b-row and reads a FULL 128-B line; every line of x read exactly once
// chip-wide. Writes: consecutive lanes = consecutive b -> full 1-KiB xT rows
// per block.
// ---------------------------------------------------------------------------
__global__ __launch_bounds__(512) void transpose_bf16_k(const float* __restrict__ x,
                                                        unsigned short* __restrict__ xT) {
    const int c0 = blockIdx.x * 32;
    const int b  = threadIdx.x;
    const float4* p = (const float4*)(x + (size_t)b * IN_DIM + c0);
    float4 v[8];
    #pragma unroll
    for (int j = 0; j < 8; ++j) v[j] = p[j];
    #pragma unroll
    for (int c = 0; c < 32; ++c) {
        xT[(size_t)(c0 + c) * B_DIM + b] = f2bf(fcomp(v[c >> 2], c));
    }
}

// ---------------------------------------------------------------------------
// Kernel 2: main. Block = 256 threads (4 waves), owns 8 outputs x all 512 b.
// Each WAVE owns 2 outputs; each LANE owns 8 b's (16 B of a bf16 row), so one
// row-gather = ONE global_load_dwordx4 per wave (1 KiB payload/instr).
// idx/w preloaded one scalar per lane, broadcast via readlane -> uniform row
// base in SGPRs, voffset = lane*16 shared across all 64 gathers.
//
// LAUNCH BOUNDS (round-5 post-mortem): (256, 8) capped the allocator at 64
// VGPRs and it emitted 32 -> accumulators SPILLED TO SCRATCH (HBM). That
// scratch traffic was the mystery +514 MB WRITE / +255 MB FETCH and the
// VALUBusy collapse in rounds 2-5 -- NOT the out-store pattern (round 5's
// full-line single-owner stores made it worse, disproving write-RMW).
// (256, 4) gives a 128-VGPR budget; actual use ~50 -> no spill, and at
// <=64 VGPRs the HW still reaches 8 waves/SIMD at runtime.
//
// Epilogue corner-turns through LDS for o-contiguous float4 out writes
// (plain cached stores; 32-B chunks measured benign at 58 MB in round 0).
// ---------------------------------------------------------------------------
#define SE 520   // epilogue LDS stride

__global__ __launch_bounds__(256, 4) void sparse_main(const unsigned short* __restrict__ xT,
                                                      const int*   __restrict__ idxp,
                                                      const float* __restrict__ wp,
                                                      const float* __restrict__ biasp,
                                                      float*       __restrict__ out) {
    __shared__ float lds[8][SE];
    const int o_blk = blockIdx.x * 8;
    const int t    = threadIdx.x;
    const int wid  = t >> 6;
    const int lane = t & 63;
    const int b8   = lane * 8;       // this thread's 8 b's

    // wave's idx/w tile: 2 o's x 32 k = 64 scalars = one per lane
    const int   iv = idxp[o_blk * K_DIM + wid * 64 + lane];
    const float wv = wp  [o_blk * K_DIM + wid * 64 + lane];

    float4 a0[2], a1[2];
    #pragma unroll
    for (int oo = 0; oo < 2; ++oo) {
        a0[oo] = make_float4(0.f, 0.f, 0.f, 0.f);
        a1[oo] = make_float4(0.f, 0.f, 0.f, 0.f);
    }

    #pragma unroll
    for (int oo = 0; oo < 2; ++oo) {
        #pragma unroll
        for (int k = 0; k < K_DIM; ++k) {
            const int L = oo * 32 + k;          // lane holding (oo,k)'s idx/w
            const int   sidx = __builtin_amdgcn_readlane(iv, L);
            const float sw   = __int_as_float(
                __builtin_amdgcn_readlane(__float_as_int(wv), L));
            const uint4 u = *(const uint4*)(xT + ((size_t)sidx << 9) + b8);
            a0[oo].x = fmaf(sw, __int_as_float(u.x << 16),          a0[oo].x);
            a0[oo].y = fmaf(sw, __int_as_float(u.x & 0xFFFF0000u),  a0[oo].y);
            a0[oo].z = fmaf(sw, __int_as_float(u.y << 16),          a0[oo].z);
            a0[oo].w = fmaf(sw, __int_as_float(u.y & 0xFFFF0000u),  a0[oo].w);
            a1[oo].x = fmaf(sw, __int_as_float(u.z << 16),          a1[oo].x);
            a1[oo].y = fmaf(sw, __int_as_float(u.z & 0xFFFF0000u),  a1[oo].y);
            a1[oo].z = fmaf(sw, __int_as_float(u.w << 16),          a1[oo].z);
            a1[oo].w = fmaf(sw, __int_as_float(u.w & 0xFFFF0000u),  a1[oo].w);
        }
    }

    #pragma unroll
    for (int oo = 0; oo < 2; ++oo) {
        const float bv = biasp[o_blk + wid * 2 + oo];
        a0[oo].x += bv; a0[oo].y += bv; a0[oo].z += bv; a0[oo].w += bv;
        a1[oo].x += bv; a1[oo].y += bv; a1[oo].z += bv; a1[oo].w += bv;
        *(float4*)(&lds[wid * 2 + oo][b8])     = a0[oo];
        *(float4*)(&lds[wid * 2 + oo][b8 + 4]) = a1[oo];
    }
    __syncthreads();

    // corner-turn write: 512 b x 8 o = 4096 floats, 4 passes of 1024
    #pragma unroll
    for (int p = 0; p < 4; ++p) {
        const int q = p * 1024 + t * 4;
        const int b = q >> 3;
        const int o = q & 7;            // 0 or 4
        float4 v;
        v.x = lds[o + 0][b];
        v.y = lds[o + 1][b];
        v.z = lds[o + 2][b];
        v.w = lds[o + 3][b];
        *(float4*)(out + (size_t)b * OUT_DIM + o_blk + o) = v;
    }
}

// ---------------------------------------------------------------------------
// Fallback (workspace too small): direct gather, correct but slow.
// ---------------------------------------------------------------------------
__global__ void sparse_fallback(const float* __restrict__ x,
                                const int*   __restrict__ idxp,
                                const float* __restrict__ wp,
                                const float* __restrict__ biasp,
                                float*       __restrict__ out) {
    const int i = blockIdx.x * blockDim.x + threadIdx.x;
    if (i >= B_DIM * OUT_DIM) return;
    const int b = i / OUT_DIM;
    const int o = i % OUT_DIM;
    float a = biasp[o];
    for (int k = 0; k < K_DIM; ++k) {
        const int idx = idxp[o * K_DIM + k];
        a = fmaf(wp[o * K_DIM + k], x[(size_t)b * IN_DIM + idx], a);
    }
    out[i] = a;
}

extern "C" void kernel_launch(void* const* d_in, const int* in_sizes, int n_in,
                              void* d_out, int out_size, void* d_ws, size_t ws_size,
                              hipStream_t stream) {
    const float* x       = (const float*)d_in[0];
    const int*   indices = (const int*)  d_in[1];
    const float* weight  = (const float*)d_in[2];
    const float* bias    = (const float*)d_in[3];
    float*       out     = (float*)d_out;

    const size_t need = (size_t)IN_DIM * B_DIM * sizeof(unsigned short);  // 64 MiB
    if (ws_size >= need) {
        unsigned short* xT = (unsigned short*)d_ws;
        transpose_bf16_k<<<IN_DIM / 32, 512, 0, stream>>>(x, xT);
        sparse_main<<<OUT_DIM / 8, 256, 0, stream>>>(xT, indices, weight, bias, out);
    } else {
        const int n = B_DIM * OUT_DIM;
        sparse_fallback<<<(n + 255) / 256, 256, 0, stream>>>(x, indices, weight, bias, out);
    }
}

// Round 7
// 311.658 us; speedup vs baseline: 1.7879x; 1.1278x over previous
//
#include <hip/hip_runtime.h>

#define B_DIM   512
#define IN_DIM  65536
#define OUT_DIM 16384
#define K_DIM   32

static __device__ __forceinline__ unsigned short f2bf(float f) {
    unsigned u = __builtin_bit_cast(unsigned, f);
    unsigned r = (u + 0x7FFFu + ((u >> 16) & 1u)) >> 16;   // round-to-nearest-even
    return (unsigned short)r;
}

static __device__ __forceinline__ float fcomp(float4 v, int c) {
    switch (c & 3) { case 0: return v.x; case 1: return v.y; case 2: return v.z; default: return v.w; }
}

// ---------------------------------------------------------------------------
// Kernel 1: transpose + fp32->bf16, NO LDS. (unchanged from round 6)
// ---------------------------------------------------------------------------
__global__ __launch_bounds__(512) void transpose_bf16_k(const float* __restrict__ x,
                                                        unsigned short* __restrict__ xT) {
    const int c0 = blockIdx.x * 32;
    const int b  = threadIdx.x;
    const float4* p = (const float4*)(x + (size_t)b * IN_DIM + c0);
    float4 v[8];
    #pragma unroll
    for (int j = 0; j < 8; ++j) v[j] = p[j];
    #pragma unroll
    for (int c = 0; c < 32; ++c) {
        xT[(size_t)(c0 + c) * B_DIM + b] = f2bf(fcomp(v[c >> 2], c));
    }
}

// ---------------------------------------------------------------------------
// Kernel 2: main. Block = 512 threads (8 waves), 8 outputs/block, ONE output
// per WAVE. Each lane owns 8 b's -> one row-gather = ONE global_load_dwordx4
// (1 KiB/wave-instr). Grid 2048 x 8 waves = 16384 waves = 64/CU supply.
//
// VGPR DISCIPLINE (rounds 0/2/3/5/6 post-mortem): the allocator consistently
// lands at HALF the launch_bounds budget (128->64, 64->32), spilling to get
// there. Round 6's 16-acc + 64-deep-unroll uint4 loop needed ~77 -> spilled
// ~13 regs -> +106 MB WRITE / +56 MB FETCH of scratch traffic. This version
// needs only ~50: 8 acc floats, two named batches of 4 uint4 (static
// indexing, <=8 loads in flight), readlane idx/w -> SGPRs. Fits the 64
// target spill-free -> 8 waves/SIMD, up to 32 waves/CU resident.
// ---------------------------------------------------------------------------
#define SE 520   // epilogue LDS stride

__global__ __launch_bounds__(512, 4) void sparse_main(const unsigned short* __restrict__ xT,
                                                      const int*   __restrict__ idxp,
                                                      const float* __restrict__ wp,
                                                      const float* __restrict__ biasp,
                                                      float*       __restrict__ out) {
    __shared__ float lds[8][SE];
    const int o_blk = blockIdx.x * 8;
    const int t    = threadIdx.x;
    const int wid  = t >> 6;         // 0..7 = this wave's output
    const int lane = t & 63;
    const int b8   = lane * 8;       // this thread's 8 b's (ushort units)
    const int o    = o_blk + wid;

    // wave's 32 idx/w scalars in lanes 0..31 (lanes 32..63 duplicate)
    const int   iv = idxp[o * K_DIM + (lane & 31)];
    const float wv = wp  [o * K_DIM + (lane & 31)];

    const unsigned short* base = xT + b8;

    float4 accL = make_float4(0.f, 0.f, 0.f, 0.f);
    float4 accH = make_float4(0.f, 0.f, 0.f, 0.f);

    uint4 A0, A1, A2, A3, B0, B1, B2, B3;
    float wA0, wA1, wA2, wA3, wB0, wB1, wB2, wB3;

#define GLOAD(dst, wdst, kk) do { \
        const int si_ = __builtin_amdgcn_readlane(iv, (kk)); \
        wdst = __int_as_float(__builtin_amdgcn_readlane(__float_as_int(wv), (kk))); \
        dst = *(const uint4*)(base + ((size_t)si_ << 9)); \
    } while (0)

#define FMA8(u, sw) do { \
        accL.x = fmaf(sw, __int_as_float(u.x << 16),         accL.x); \
        accL.y = fmaf(sw, __int_as_float(u.x & 0xFFFF0000u), accL.y); \
        accL.z = fmaf(sw, __int_as_float(u.y << 16),         accL.z); \
        accL.w = fmaf(sw, __int_as_float(u.y & 0xFFFF0000u), accL.w); \
        accH.x = fmaf(sw, __int_as_float(u.z << 16),         accH.x); \
        accH.y = fmaf(sw, __int_as_float(u.z & 0xFFFF0000u), accH.y); \
        accH.z = fmaf(sw, __int_as_float(u.w << 16),         accH.z); \
        accH.w = fmaf(sw, __int_as_float(u.w & 0xFFFF0000u), accH.w); \
    } while (0)

    // double-buffered: batch A = k0..k0+3, batch B = next 4; <=8 loads in flight
    GLOAD(A0, wA0,  0); GLOAD(A1, wA1,  1); GLOAD(A2, wA2,  2); GLOAD(A3, wA3,  3);
    GLOAD(B0, wB0,  4); GLOAD(B1, wB1,  5); GLOAD(B2, wB2,  6); GLOAD(B3, wB3,  7);
    FMA8(A0, wA0); FMA8(A1, wA1); FMA8(A2, wA2); FMA8(A3, wA3);
    GLOAD(A0, wA0,  8); GLOAD(A1, wA1,  9); GLOAD(A2, wA2, 10); GLOAD(A3, wA3, 11);
    FMA8(B0, wB0); FMA8(B1, wB1); FMA8(B2, wB2); FMA8(B3, wB3);
    GLOAD(B0, wB0, 12); GLOAD(B1, wB1, 13); GLOAD(B2, wB2, 14); GLOAD(B3, wB3, 15);
    FMA8(A0, wA0); FMA8(A1, wA1); FMA8(A2, wA2); FMA8(A3, wA3);
    GLOAD(A0, wA0, 16); GLOAD(A1, wA1, 17); GLOAD(A2, wA2, 18); GLOAD(A3, wA3, 19);
    FMA8(B0, wB0); FMA8(B1, wB1); FMA8(B2, wB2); FMA8(B3, wB3);
    GLOAD(B0, wB0, 20); GLOAD(B1, wB1, 21); GLOAD(B2, wB2, 22); GLOAD(B3, wB3, 23);
    FMA8(A0, wA0); FMA8(A1, wA1); FMA8(A2, wA2); FMA8(A3, wA3);
    GLOAD(A0, wA0, 24); GLOAD(A1, wA1, 25); GLOAD(A2, wA2, 26); GLOAD(A3, wA3, 27);
    FMA8(B0, wB0); FMA8(B1, wB1); FMA8(B2, wB2); FMA8(B3, wB3);
    GLOAD(B0, wB0, 28); GLOAD(B1, wB1, 29); GLOAD(B2, wB2, 30); GLOAD(B3, wB3, 31);
    FMA8(A0, wA0); FMA8(A1, wA1); FMA8(A2, wA2); FMA8(A3, wA3);
    FMA8(B0, wB0); FMA8(B1, wB1); FMA8(B2, wB2); FMA8(B3, wB3);

#undef GLOAD
#undef FMA8

    const float bv = biasp[o];
    accL.x += bv; accL.y += bv; accL.z += bv; accL.w += bv;
    accH.x += bv; accH.y += bv; accH.z += bv; accH.w += bv;
    *(float4*)(&lds[wid][b8])     = accL;
    *(float4*)(&lds[wid][b8 + 4]) = accH;
    __syncthreads();

    // corner-turn write: 512 b x 8 o = 4096 floats, 2 passes of 2048
    // (same memory pattern as round 0's epilogue: WRITE measured 59 MB there)
    #pragma unroll
    for (int p = 0; p < 2; ++p) {
        const int q = p * 2048 + t * 4;
        const int b = q >> 3;
        const int oo = q & 7;            // 0 or 4
        float4 v;
        v.x = lds[oo + 0][b];
        v.y = lds[oo + 1][b];
        v.z = lds[oo + 2][b];
        v.w = lds[oo + 3][b];
        *(float4*)(out + (size_t)b * OUT_DIM + o_blk + oo) = v;
    }
}

// ---------------------------------------------------------------------------
// Fallback (workspace too small): direct gather, correct but slow.
// ---------------------------------------------------------------------------
__global__ void sparse_fallback(const float* __restrict__ x,
                                const int*   __restrict__ idxp,
                                const float* __restrict__ wp,
                                const float* __restrict__ biasp,
                                float*       __restrict__ out) {
    const int i = blockIdx.x * blockDim.x + threadIdx.x;
    if (i >= B_DIM * OUT_DIM) return;
    const int b = i / OUT_DIM;
    const int o = i % OUT_DIM;
    float a = biasp[o];
    for (int k = 0; k < K_DIM; ++k) {
        const int idx = idxp[o * K_DIM + k];
        a = fmaf(wp[o * K_DIM + k], x[(size_t)b * IN_DIM + idx], a);
    }
    out[i] = a;
}

extern "C" void kernel_launch(void* const* d_in, const int* in_sizes, int n_in,
                              void* d_out, int out_size, void* d_ws, size_t ws_size,
                              hipStream_t stream) {
    const float* x       = (const float*)d_in[0];
    const int*   indices = (const int*)  d_in[1];
    const float* weight  = (const float*)d_in[2];
    const float* bias    = (const float*)d_in[3];
    float*       out     = (float*)d_out;

    const size_t need = (size_t)IN_DIM * B_DIM * sizeof(unsigned short);  // 64 MiB
    if (ws_size >= need) {
        unsigned short* xT = (unsigned short*)d_ws;
        transpose_bf16_k<<<IN_DIM / 32, 512, 0, stream>>>(x, xT);
        sparse_main<<<OUT_DIM / 8, 512, 0, stream>>>(xT, indices, weight, bias, out);
    } else {
        const int n = B_DIM * OUT_DIM;
        sparse_fallback<<<(n + 255) / 256, 256, 0, stream>>>(x, indices, weight, bias, out);
    }
}

// Round 8
// 309.441 us; speedup vs baseline: 1.8007x; 1.0072x over previous
//
#include <hip/hip_runtime.h>

#define B_DIM   512
#define IN_DIM  65536
#define OUT_DIM 16384
#define K_DIM   32

static __device__ __forceinline__ unsigned short f2bf(float f) {
    unsigned u = __builtin_bit_cast(unsigned, f);
    unsigned r = (u + 0x7FFFu + ((u >> 16) & 1u)) >> 16;   // round-to-nearest-even
    return (unsigned short)r;
}

static __device__ __forceinline__ float fcomp(float4 v, int c) {
    switch (c & 3) { case 0: return v.x; case 1: return v.y; case 2: return v.z; default: return v.w; }
}

// ---------------------------------------------------------------------------
// Kernel 1: transpose + fp32->bf16 via LDS corner-turn.
// Block = 512 threads (8 waves), tile = 32 in-cols x all 512 b.
// READ (unchanged): each thread owns one b-row, reads a FULL 128-B line.
// NEW WRITE PATH (round-7 post-mortem): the old version stored 2 B/lane
// (128-B partial-line wave-stores, 524K instrs) and ran ~130 us vs a ~32 us
// traffic floor. Now: stage bf16 tile in LDS [32][512] (32 KiB), then each
// wave writes 4 complete 1-KiB xT rows, one global_store_dwordx4 per row
// (64 lanes x 16 B = the whole row, single-owner, full-line).
// LDS banks: b16 writes at 2-B stride = 2 lanes/word = free (m136);
// b128 reads of contiguous 1 KiB = the canonical conflict-free pattern.
// ---------------------------------------------------------------------------
__global__ __launch_bounds__(512) void transpose_bf16_k(const float* __restrict__ x,
                                                        unsigned short* __restrict__ xT) {
    __shared__ unsigned short tile[32][512];   // 32 KiB
    const int c0 = blockIdx.x * 32;
    const int t  = threadIdx.x;                // = this thread's b row
    const float4* p = (const float4*)(x + (size_t)t * IN_DIM + c0);
    float4 v[8];
    #pragma unroll
    for (int j = 0; j < 8; ++j) v[j] = p[j];
    #pragma unroll
    for (int c = 0; c < 32; ++c)
        tile[c][t] = f2bf(fcomp(v[c >> 2], c));
    __syncthreads();

    // 8 waves x 4 rows each: wave w stores rows c = w*4..w*4+3 whole.
    const int wid  = t >> 6;
    const int lane = t & 63;
    #pragma unroll
    for (int r = 0; r < 4; ++r) {
        const int c = wid * 4 + r;
        const uint4 d = *(const uint4*)(&tile[c][lane * 8]);
        *(uint4*)(xT + (size_t)(c0 + c) * B_DIM + lane * 8) = d;
    }
}

// ---------------------------------------------------------------------------
// Kernel 2: main — UNCHANGED from round 7 (verified: 90 us, VGPR=64 no spill,
// WRITE 36.9 MB clean). Block = 512 threads (8 waves), one output per wave,
// lane owns 8 b's -> one row-gather = ONE global_load_dwordx4 (1 KiB/instr),
// two named batches of 4 uint4 (static indexing, <=8 loads in flight).
// Known wall (rounds 0 vs 7): FETCH ~253 MB at ~2.8-3.3 TB/s L2-miss BW is
// invariant across gather-instr-count changes -> L2-miss service path bound.
// ---------------------------------------------------------------------------
#define SE 520   // epilogue LDS stride

__global__ __launch_bounds__(512, 4) void sparse_main(const unsigned short* __restrict__ xT,
                                                      const int*   __restrict__ idxp,
                                                      const float* __restrict__ wp,
                                                      const float* __restrict__ biasp,
                                                      float*       __restrict__ out) {
    __shared__ float lds[8][SE];
    const int o_blk = blockIdx.x * 8;
    const int t    = threadIdx.x;
    const int wid  = t >> 6;         // 0..7 = this wave's output
    const int lane = t & 63;
    const int b8   = lane * 8;       // this thread's 8 b's (ushort units)
    const int o    = o_blk + wid;

    // wave's 32 idx/w scalars in lanes 0..31 (lanes 32..63 duplicate)
    const int   iv = idxp[o * K_DIM + (lane & 31)];
    const float wv = wp  [o * K_DIM + (lane & 31)];

    const unsigned short* base = xT + b8;

    float4 accL = make_float4(0.f, 0.f, 0.f, 0.f);
    float4 accH = make_float4(0.f, 0.f, 0.f, 0.f);

    uint4 A0, A1, A2, A3, B0, B1, B2, B3;
    float wA0, wA1, wA2, wA3, wB0, wB1, wB2, wB3;

#define GLOAD(dst, wdst, kk) do { \
        const int si_ = __builtin_amdgcn_readlane(iv, (kk)); \
        wdst = __int_as_float(__builtin_amdgcn_readlane(__float_as_int(wv), (kk))); \
        dst = *(const uint4*)(base + ((size_t)si_ << 9)); \
    } while (0)

#define FMA8(u, sw) do { \
        accL.x = fmaf(sw, __int_as_float(u.x << 16),         accL.x); \
        accL.y = fmaf(sw, __int_as_float(u.x & 0xFFFF0000u), accL.y); \
        accL.z = fmaf(sw, __int_as_float(u.y << 16),         accL.z); \
        accL.w = fmaf(sw, __int_as_float(u.y & 0xFFFF0000u), accL.w); \
        accH.x = fmaf(sw, __int_as_float(u.z << 16),         accH.x); \
        accH.y = fmaf(sw, __int_as_float(u.z & 0xFFFF0000u), accH.y); \
        accH.z = fmaf(sw, __int_as_float(u.w << 16),         accH.z); \
        accH.w = fmaf(sw, __int_as_float(u.w & 0xFFFF0000u), accH.w); \
    } while (0)

    // double-buffered: batch A = k0..k0+3, batch B = next 4; <=8 loads in flight
    GLOAD(A0, wA0,  0); GLOAD(A1, wA1,  1); GLOAD(A2, wA2,  2); GLOAD(A3, wA3,  3);
    GLOAD(B0, wB0,  4); GLOAD(B1, wB1,  5); GLOAD(B2, wB2,  6); GLOAD(B3, wB3,  7);
    FMA8(A0, wA0); FMA8(A1, wA1); FMA8(A2, wA2); FMA8(A3, wA3);
    GLOAD(A0, wA0,  8); GLOAD(A1, wA1,  9); GLOAD(A2, wA2, 10); GLOAD(A3, wA3, 11);
    FMA8(B0, wB0); FMA8(B1, wB1); FMA8(B2, wB2); FMA8(B3, wB3);
    GLOAD(B0, wB0, 12); GLOAD(B1, wB1, 13); GLOAD(B2, wB2, 14); GLOAD(B3, wB3, 15);
    FMA8(A0, wA0); FMA8(A1, wA1); FMA8(A2, wA2); FMA8(A3, wA3);
    GLOAD(A0, wA0, 16); GLOAD(A1, wA1, 17); GLOAD(A2, wA2, 18); GLOAD(A3, wA3, 19);
    FMA8(B0, wB0); FMA8(B1, wB1); FMA8(B2, wB2); FMA8(B3, wB3);
    GLOAD(B0, wB0, 20); GLOAD(B1, wB1, 21); GLOAD(B2, wB2, 22); GLOAD(B3, wB3, 23);
    FMA8(A0, wA0); FMA8(A1, wA1); FMA8(A2, wA2); FMA8(A3, wA3);
    GLOAD(A0, wA0, 24); GLOAD(A1, wA1, 25); GLOAD(A2, wA2, 26); GLOAD(A3, wA3, 27);
    FMA8(B0, wB0); FMA8(B1, wB1); FMA8(B2, wB2); FMA8(B3, wB3);
    GLOAD(B0, wB0, 28); GLOAD(B1, wB1, 29); GLOAD(B2, wB2, 30); GLOAD(B3, wB3, 31);
    FMA8(A0, wA0); FMA8(A1, wA1); FMA8(A2, wA2); FMA8(A3, wA3);
    FMA8(B0, wB0); FMA8(B1, wB1); FMA8(B2, wB2); FMA8(B3, wB3);

#undef GLOAD
#undef FMA8

    const float bv = biasp[o];
    accL.x += bv; accL.y += bv; accL.z += bv; accL.w += bv;
    accH.x += bv; accH.y += bv; accH.z += bv; accH.w += bv;
    *(float4*)(&lds[wid][b8])     = accL;
    *(float4*)(&lds[wid][b8 + 4]) = accH;
    __syncthreads();

    // corner-turn write: 512 b x 8 o = 4096 floats, 2 passes of 2048
    #pragma unroll
    for (int p = 0; p < 2; ++p) {
        const int q = p * 2048 + t * 4;
        const int b = q >> 3;
        const int oo = q & 7;            // 0 or 4
        float4 v;
        v.x = lds[oo + 0][b];
        v.y = lds[oo + 1][b];
        v.z = lds[oo + 2][b];
        v.w = lds[oo + 3][b];
        *(float4*)(out + (size_t)b * OUT_DIM + o_blk + oo) = v;
    }
}

// ---------------------------------------------------------------------------
// Fallback (workspace too small): direct gather, correct but slow.
// ---------------------------------------------------------------------------
__global__ void sparse_fallback(const float* __restrict__ x,
                                const int*   __restrict__ idxp,
                                const float* __restrict__ wp,
                                const float* __restrict__ biasp,
                                float*       __restrict__ out) {
    const int i = blockIdx.x * blockDim.x + threadIdx.x;
    if (i >= B_DIM * OUT_DIM) return;
    const int b = i / OUT_DIM;
    const int o = i % OUT_DIM;
    float a = biasp[o];
    for (int k = 0; k < K_DIM; ++k) {
        const int idx = idxp[o * K_DIM + k];
        a = fmaf(wp[o * K_DIM + k], x[(size_t)b * IN_DIM + idx], a);
    }
    out[i] = a;
}

extern "C" void kernel_launch(void* const* d_in, const int* in_sizes, int n_in,
                              void* d_out, int out_size, void* d_ws, size_t ws_size,
                              hipStream_t stream) {
    const float* x       = (const float*)d_in[0];
    const int*   indices = (const int*)  d_in[1];
    const float* weight  = (const float*)d_in[2];
    const float* bias    = (const float*)d_in[3];
    float*       out     = (float*)d_out;

    const size_t need = (size_t)IN_DIM * B_DIM * sizeof(unsigned short);  // 64 MiB
    if (ws_size >= need) {
        unsigned short* xT = (unsigned short*)d_ws;
        transpose_bf16_k<<<IN_DIM / 32, 512, 0, stream>>>(x, xT);
        sparse_main<<<OUT_DIM / 8, 512, 0, stream>>>(xT, indices, weight, bias, out);
    } else {
        const int n = B_DIM * OUT_DIM;
        sparse_fallback<<<(n + 255) / 256, 256, 0, stream>>>(x, indices, weight, bias, out);
    }
}